// Round 1
// baseline (258.174 us; speedup 1.0000x reference)
//
#include <hip/hip_runtime.h>

// SSIM loss, fp32, B=16 C=3 H=W=512, 11x11 Gaussian (sigma=1.5), zero-padded.
// Separable conv: horizontal pass into LDS, vertical pass + SSIM + reduction.

#define IMG_W 512
#define IMG_H 512
#define PLANES 48           // B*C = 16*3
#define TX 64               // output tile width
#define TY 16               // output tile height
#define RAD 5
#define KW 11
#define LX (TX + 2 * RAD)   // 74
#define LY (TY + 2 * RAD)   // 26
#define NTHREADS 256

__global__ __launch_bounds__(NTHREADS) void ssim_tile_kernel(
    const float* __restrict__ x, const float* __restrict__ y,
    double* __restrict__ acc)
{
    __shared__ float sx[LY][LX];
    __shared__ float sy[LY][LX];
    __shared__ float hb[5][LY][TX];   // horizontally blurred x, y, x2, y2, xy

    // Gaussian weights (normalized). Cheap per-thread compute, once.
    float w[KW];
    {
        float s = 0.f;
        #pragma unroll
        for (int k = 0; k < KW; ++k) {
            float d = (float)(k - RAD);
            w[k] = expf(-d * d / (2.f * 1.5f * 1.5f));
            s += w[k];
        }
        #pragma unroll
        for (int k = 0; k < KW; ++k) w[k] /= s;
    }

    const int plane = blockIdx.z;
    const float* __restrict__ xp = x + (size_t)plane * IMG_H * IMG_W;
    const float* __restrict__ yp = y + (size_t)plane * IMG_H * IMG_W;
    const int tx0 = blockIdx.x * TX - RAD;
    const int ty0 = blockIdx.y * TY - RAD;
    const int tid = threadIdx.x;

    // Stage input tiles (zero-padded at image borders -> matches conv zero pad).
    for (int idx = tid; idx < LY * LX; idx += NTHREADS) {
        int r = idx / LX, c = idx - r * LX;
        int gy = ty0 + r, gx = tx0 + c;
        float xv = 0.f, yv = 0.f;
        if (gx >= 0 && gx < IMG_W && gy >= 0 && gy < IMG_H) {
            size_t o = (size_t)gy * IMG_W + gx;
            xv = xp[o];
            yv = yp[o];
        }
        sx[r][c] = xv;
        sy[r][c] = yv;
    }
    __syncthreads();

    // Horizontal 11-tap pass for 5 quantities.
    for (int idx = tid; idx < LY * TX; idx += NTHREADS) {
        int r = idx / TX, j = idx - r * TX;
        float bx = 0.f, by = 0.f, bxx = 0.f, byy = 0.f, bxy = 0.f;
        #pragma unroll
        for (int k = 0; k < KW; ++k) {
            float a = sx[r][j + k];
            float b = sy[r][j + k];
            float wk = w[k];
            bx  += wk * a;
            by  += wk * b;
            bxx += wk * a * a;
            byy += wk * b * b;
            bxy += wk * a * b;
        }
        hb[0][r][j] = bx;
        hb[1][r][j] = by;
        hb[2][r][j] = bxx;
        hb[3][r][j] = byy;
        hb[4][r][j] = bxy;
    }
    __syncthreads();

    // Vertical 11-tap pass + SSIM map + local accumulation.
    float local = 0.f;
    for (int idx = tid; idx < TY * TX; idx += NTHREADS) {
        int i = idx / TX, j = idx - i * TX;
        float mx = 0.f, my = 0.f, xx = 0.f, yy = 0.f, xy = 0.f;
        #pragma unroll
        for (int k = 0; k < KW; ++k) {
            float wk = w[k];
            mx += wk * hb[0][i + k][j];
            my += wk * hb[1][i + k][j];
            xx += wk * hb[2][i + k][j];
            yy += wk * hb[3][i + k][j];
            xy += wk * hb[4][i + k][j];
        }
        float mx2 = mx * mx, my2 = my * my, mxy = mx * my;
        float sx2 = xx - mx2, sy2 = yy - my2, sxy = xy - mxy;
        const float c1 = 0.01f * 0.01f;   // (0.01*DATA_RANGE)^2
        const float c2 = 0.03f * 0.03f;   // (0.03*DATA_RANGE)^2
        float num = (2.f * mxy + c1) * (2.f * sxy + c2);
        float den = (mx2 + my2 + c1) * (sx2 + sy2 + c2) + 1e-8f;
        local += num / den;
    }

    // Block reduction: wave shuffle -> LDS -> one double atomic per block.
    #pragma unroll
    for (int off = 32; off > 0; off >>= 1)
        local += __shfl_down(local, off, 64);

    __shared__ float wave_sums[NTHREADS / 64];
    int lane = tid & 63, wv = tid >> 6;
    if (lane == 0) wave_sums[wv] = local;
    __syncthreads();
    if (tid == 0) {
        float s = 0.f;
        #pragma unroll
        for (int i = 0; i < NTHREADS / 64; ++i) s += wave_sums[i];
        atomicAdd(acc, (double)s);
    }
}

__global__ void ssim_finalize_kernel(const double* __restrict__ acc,
                                     float* __restrict__ out)
{
    const double n = (double)PLANES * IMG_H * IMG_W;
    out[0] = (float)(1.0 - acc[0] / n);
}

extern "C" void kernel_launch(void* const* d_in, const int* in_sizes, int n_in,
                              void* d_out, int out_size, void* d_ws, size_t ws_size,
                              hipStream_t stream)
{
    const float* x = (const float*)d_in[0];
    const float* y = (const float*)d_in[1];
    float* out = (float*)d_out;
    double* acc = (double*)d_ws;

    hipMemsetAsync(acc, 0, sizeof(double), stream);

    dim3 grid(IMG_W / TX, IMG_H / TY, PLANES);
    ssim_tile_kernel<<<grid, NTHREADS, 0, stream>>>(x, y, acc);
    ssim_finalize_kernel<<<1, 1, 0, stream>>>(acc, out);
}

// Round 2
// 177.518 us; speedup vs baseline: 1.4544x; 1.4544x over previous
//
#include <hip/hip_runtime.h>
#include <math.h>

// SSIM loss, fp32, B=16 C=3 H=W=512, 11x11 Gaussian (sigma=1.5), zero pad.
// R2: LDS-traffic-minimized separable conv.
//  - horizontal: register sliding window straight from global (float4 loads)
//  - hb stored TRANSPOSED in LDS -> vertical pass reads contiguous columns
//  - vertical: 1 col x 8 output rows per thread, 40 register accumulators
//  - per-block partial sums -> d_ws (no memset, no atomics), finalize reduces

#define IMG_W 512
#define IMG_H 512
#define PLANES 48           // B*C
#define TX 64
#define TY 32
#define RAD 5
#define KW 11
#define LY (TY + 2 * RAD)   // 42 hb rows per tile
#define LYP 42              // col stride: 2-way read conflict (free), 3 blk/CU
#define NT 256
#define GDX (IMG_W / TX)    // 8
#define GDY (IMG_H / TY)    // 16
#define NBLK (GDX * GDY * PLANES)  // 6144

__global__ __launch_bounds__(NT, 2) void ssim_tile_kernel(
    const float* __restrict__ x, const float* __restrict__ y,
    float* __restrict__ partials)
{
    __shared__ float hbT[5][TX][LYP];   // 52.5 KB -> 3 blocks/CU
    __shared__ float wave_sums[NT / 64];

    // Normalized 1D Gaussian weights (computed once per thread).
    float w[KW];
    {
        float s = 0.f;
        #pragma unroll
        for (int k = 0; k < KW; ++k) {
            float d = (float)(k - RAD);
            w[k] = expf(-d * d * (1.f / (2.f * 1.5f * 1.5f)));
            s += w[k];
        }
        float inv = 1.f / s;
        #pragma unroll
        for (int k = 0; k < KW; ++k) w[k] *= inv;
    }

    const int tid = threadIdx.x;
    const int plane = blockIdx.z;
    const float* __restrict__ xp = x + (size_t)plane * IMG_H * IMG_W;
    const float* __restrict__ yp = y + (size_t)plane * IMG_H * IMG_W;
    const int bx0 = blockIdx.x * TX;
    const int ty0 = blockIdx.y * TY - RAD;   // image row of hb row 0

    // ---- Horizontal pass: 8-wide output groups, sliding window in regs ----
    // Group covers inputs [j0-5, j0+12]; we load [j0-8, j0+16) as 6 float4.
    // All float4 offsets are multiples of 4 -> never straddle image edges.
    for (int idx = tid; idx < LY * 8; idx += NT) {
        const int r  = idx >> 3;       // hb row 0..41
        const int g  = idx & 7;        // 8-col group within tile
        const int gy = ty0 + r;
        const int j0 = bx0 + g * 8;    // global col of first output

        float av[24], bv[24];
        if (gy >= 0 && gy < IMG_H) {
            const float* rowx = xp + (size_t)gy * IMG_W;
            const float* rowy = yp + (size_t)gy * IMG_W;
            #pragma unroll
            for (int v = 0; v < 6; ++v) {
                const int gx = j0 - 8 + 4 * v;
                float4 xa, ya;
                if (gx >= 0 && gx < IMG_W) {
                    xa = *(const float4*)(rowx + gx);
                    ya = *(const float4*)(rowy + gx);
                } else {
                    xa = make_float4(0.f, 0.f, 0.f, 0.f);
                    ya = make_float4(0.f, 0.f, 0.f, 0.f);
                }
                av[4*v+0] = xa.x; av[4*v+1] = xa.y; av[4*v+2] = xa.z; av[4*v+3] = xa.w;
                bv[4*v+0] = ya.x; bv[4*v+1] = ya.y; bv[4*v+2] = ya.z; bv[4*v+3] = ya.w;
            }
        } else {
            #pragma unroll
            for (int i = 0; i < 24; ++i) { av[i] = 0.f; bv[i] = 0.f; }
        }

        // Products once per input (5-FMA taps instead of 8-VALU taps).
        float AA[18], BB[18], AB[18];
        #pragma unroll
        for (int i = 0; i < 18; ++i) {
            float A = av[i + 3], B = bv[i + 3];
            AA[i] = A * A; BB[i] = B * B; AB[i] = A * B;
        }

        #pragma unroll
        for (int u = 0; u < 8; ++u) {
            float sxv = 0.f, syv = 0.f, sxx = 0.f, syy = 0.f, sxy = 0.f;
            #pragma unroll
            for (int k = 0; k < KW; ++k) {
                const float wk = w[k];
                sxv += wk * av[u + 3 + k];
                syv += wk * bv[u + 3 + k];
                sxx += wk * AA[u + k];
                syy += wk * BB[u + k];
                sxy += wk * AB[u + k];
            }
            const int c = g * 8 + u;   // local col 0..63
            hbT[0][c][r] = sxv;
            hbT[1][c][r] = syv;
            hbT[2][c][r] = sxx;
            hbT[3][c][r] = syy;
            hbT[4][c][r] = sxy;
        }
    }
    __syncthreads();

    // ---- Vertical pass: 1 column x 8 output rows per thread ----
    const int j  = tid & 63;          // local col
    const int i0 = (tid >> 6) * 8;    // first output row of this chunk

    float aX[8], aY[8], aXX[8], aYY[8], aXY[8];
    #pragma unroll
    for (int u = 0; u < 8; ++u) {
        aX[u] = 0.f; aY[u] = 0.f; aXX[u] = 0.f; aYY[u] = 0.f; aXY[u] = 0.f;
    }

    #pragma unroll
    for (int rr = 0; rr < 18; ++rr) {     // hb rows i0 .. i0+17
        const int r = i0 + rr;
        const float hX  = hbT[0][j][r];
        const float hY  = hbT[1][j][r];
        const float hXX = hbT[2][j][r];
        const float hYY = hbT[3][j][r];
        const float hXY = hbT[4][j][r];
        const int ulo = (rr - 10) > 0 ? (rr - 10) : 0;
        const int uhi = rr < 7 ? rr : 7;
        #pragma unroll
        for (int u = ulo; u <= uhi; ++u) {
            const float wk = w[rr - u];   // tap index = r - (i0+u)
            aX[u]  += wk * hX;
            aY[u]  += wk * hY;
            aXX[u] += wk * hXX;
            aYY[u] += wk * hYY;
            aXY[u] += wk * hXY;
        }
    }

    // ---- SSIM map + local sum ----
    float local = 0.f;
    #pragma unroll
    for (int u = 0; u < 8; ++u) {
        const float mx = aX[u], my = aY[u];
        const float mx2 = mx * mx, my2 = my * my, mxy = mx * my;
        const float sx2 = aXX[u] - mx2, sy2 = aYY[u] - my2, sxy = aXY[u] - mxy;
        const float c1 = 1e-4f, c2 = 9e-4f;
        const float num = (2.f * mxy + c1) * (2.f * sxy + c2);
        const float den = (mx2 + my2 + c1) * (sx2 + sy2 + c2) + 1e-8f;
        local += num * __builtin_amdgcn_rcpf(den);
    }

    // ---- Block reduction -> one partial per block ----
    #pragma unroll
    for (int off = 32; off > 0; off >>= 1)
        local += __shfl_down(local, off, 64);
    const int lane = tid & 63, wv = tid >> 6;
    if (lane == 0) wave_sums[wv] = local;
    __syncthreads();
    if (tid == 0) {
        float s = wave_sums[0] + wave_sums[1] + wave_sums[2] + wave_sums[3];
        const int bid = blockIdx.x + GDX * (blockIdx.y + GDY * blockIdx.z);
        partials[bid] = s;
    }
}

__global__ __launch_bounds__(NT) void ssim_finalize_kernel(
    const float* __restrict__ partials, float* __restrict__ out)
{
    const int tid = threadIdx.x;
    double s = 0.0;
    for (int i = tid; i < NBLK; i += NT) s += (double)partials[i];
    #pragma unroll
    for (int off = 32; off > 0; off >>= 1)
        s += __shfl_down(s, off, 64);
    __shared__ double ws_[NT / 64];
    const int lane = tid & 63, wv = tid >> 6;
    if (lane == 0) ws_[wv] = s;
    __syncthreads();
    if (tid == 0) {
        double t = ws_[0] + ws_[1] + ws_[2] + ws_[3];
        const double n = (double)PLANES * IMG_H * IMG_W;
        out[0] = (float)(1.0 - t / n);
    }
}

extern "C" void kernel_launch(void* const* d_in, const int* in_sizes, int n_in,
                              void* d_out, int out_size, void* d_ws, size_t ws_size,
                              hipStream_t stream)
{
    const float* x = (const float*)d_in[0];
    const float* y = (const float*)d_in[1];
    float* out = (float*)d_out;
    float* partials = (float*)d_ws;   // NBLK floats, fully overwritten each call

    dim3 grid(GDX, GDY, PLANES);
    ssim_tile_kernel<<<grid, NT, 0, stream>>>(x, y, partials);
    ssim_finalize_kernel<<<1, NT, 0, stream>>>(partials, out);
}